// Round 15
// baseline (90.839 us; speedup 1.0000x reference)
//
#include <hip/hip_runtime.h>
#include <math.h>

#define NN 4096
#define CC 256
#define HH 8
#define DHD 32
#define EE 32768
#define FW 128   // bitset words per row (4096/32)
#define MAXD 64  // fixed CSR slots per dst (Poisson(8): P(deg>64) ~ 1e-35)

typedef float f32x4 __attribute__((ext_vector_type(4)));
typedef __bf16 bf16x8 __attribute__((ext_vector_type(8)));
typedef __bf16 bf16x4 __attribute__((ext_vector_type(4)));

__device__ __forceinline__ int bucketf(int d){
  float l = log2f((float)d + 1.0f);
  int b = (int)floorf(l);
  return b < 0 ? 0 : (b > 8 ? 8 : b);
}

// single pass: outdeg + cursor(=indeg) atomics + fixed-slot CSR scatter
__global__ void k_scatter(const int* __restrict__ src, const int* __restrict__ dst,
                          int* __restrict__ cursor, int* __restrict__ outdeg,
                          int* __restrict__ nsrc){
  int e = blockIdx.x*256+threadIdx.x;
  if(e<EE){
    int d = dst[e], s = src[e];
    atomicAdd(&outdeg[s],1);
    int p = atomicAdd(&cursor[d],1);
    if(p < MAXD) nsrc[d*MAXD+p] = s;
  }
}

// merged: blocks [0,2048) build F1 (2 rows each); blocks [2048,3072) do
// x_in = x + deg embeds ; xn = LN1(x_in) (4 nodes each).
__global__ void k_mid(const int* __restrict__ cursor, const int* __restrict__ nsrc,
                      unsigned* __restrict__ F1,
                      const float* __restrict__ x,
                      const int* __restrict__ outdeg, const float* __restrict__ iemb,
                      const float* __restrict__ oemb, const float* __restrict__ g,
                      const float* __restrict__ be, float* __restrict__ x_in,
                      __bf16* __restrict__ xn){
  int b = blockIdx.x;
  int tid = threadIdx.x;
  if(b < 2048){
    int d = b*2 + (tid>>7);
    int w = tid & 127;
    int cdeg = cursor[d]; if(cdeg > MAXD) cdeg = MAXD;
    const int* row = nsrc + d*MAXD;
    unsigned v = 0;
    for(int i=0;i<cdeg;i++){
      int s = row[i];
      if((s>>5) == w) v |= 1u << (s&31);
    }
    F1[(size_t)d*FW + w] = v;
    return;
  }
  int node = (b-2048)*4 + (tid >> 6);
  int lane = tid & 63;
  int bi = bucketf(cursor[node]);   // cursor = true indeg (uncapped count)
  int bo = bucketf(outdeg[node]);
  float4 xv = ((const float4*)(x + (size_t)node*CC))[lane];
  float4 iv = ((const float4*)(iemb + (size_t)bi*CC))[lane];
  float4 ov = ((const float4*)(oemb + (size_t)bo*CC))[lane];
  float4 v;
  v.x = xv.x+iv.x+ov.x; v.y = xv.y+iv.y+ov.y;
  v.z = xv.z+iv.z+ov.z; v.w = xv.w+iv.w+ov.w;
  ((float4*)(x_in + (size_t)node*CC))[lane] = v;
  float s  = v.x+v.y+v.z+v.w;
  float sq = v.x*v.x+v.y*v.y+v.z*v.z+v.w*v.w;
  #pragma unroll
  for(int m=32;m>=1;m>>=1){ s += __shfl_xor(s,m); sq += __shfl_xor(sq,m); }
  float mu  = s * (1.0f/CC);
  float var = sq * (1.0f/CC) - mu*mu;
  float inv = rsqrtf(var + 1e-5f);
  float4 gv = ((const float4*)g)[lane];
  float4 bv = ((const float4*)be)[lane];
  bf16x4 o;
  o[0] = (__bf16)(gv.x*(v.x-mu)*inv + bv.x);
  o[1] = (__bf16)(gv.y*(v.y-mu)*inv + bv.y);
  o[2] = (__bf16)(gv.z*(v.z-mu)*inv + bv.z);
  o[3] = (__bf16)(gv.w*(v.w-mu)*inv + bv.w);
  *(bf16x4*)(xn + (size_t)node*CC + lane*4) = o;
}

// weight transposes (fp32 [K,N] -> bf16 [N,K]) + qkv bias concat + counter zero.
__global__ void k_pre(const float* __restrict__ Wq, const float* __restrict__ Wk,
                      const float* __restrict__ Wv, const float* __restrict__ Wo,
                      const float* __restrict__ W1, const float* __restrict__ W2,
                      const float* __restrict__ bq, const float* __restrict__ bk,
                      const float* __restrict__ bv,
                      __bf16* __restrict__ WqkvT, __bf16* __restrict__ WoT,
                      __bf16* __restrict__ W1T, __bf16* __restrict__ W2T,
                      float* __restrict__ bqkv, int* __restrict__ zero_base){
  int b = blockIdx.x;
  int tid = threadIdx.x;
  if(b >= 193){
    zero_base[(b-193)*256 + tid] = 0;   // cursor|outdeg = 8192 ints
    return;
  }
  if(b == 192){
    bqkv[tid]     = bq[tid];
    bqkv[256+tid] = bk[tid];
    bqkv[512+tid] = bv[tid];
    return;
  }
  const float* W; __bf16* Wt; int K, N, tile;
  if(b < 16)      { W=Wq; Wt=WqkvT;        K=256;  N=256;  tile=b; }
  else if(b < 32) { W=Wk; Wt=WqkvT+65536;  K=256;  N=256;  tile=b-16; }
  else if(b < 48) { W=Wv; Wt=WqkvT+131072; K=256;  N=256;  tile=b-32; }
  else if(b < 64) { W=Wo; Wt=WoT;          K=256;  N=256;  tile=b-48; }
  else if(b < 128){ W=W1; Wt=W1T;          K=256;  N=1024; tile=b-64; }
  else            { W=W2; Wt=W2T;          K=1024; N=256;  tile=b-128; }
  int nK = K/64;
  int tk = tile % nK, tn = tile / nK;
  __shared__ float T[64][65];
  int c = tid & 63, r0 = tid >> 6;
  #pragma unroll
  for(int i=0;i<16;i++){
    int row = r0*16 + i;
    T[row][c] = W[(size_t)(tk*64+row)*N + tn*64 + c];
  }
  __syncthreads();
  #pragma unroll
  for(int i=0;i<16;i++){
    int row = r0*16 + i;
    Wt[(size_t)(tn*64+row)*K + tk*64 + c] = (__bf16)T[c][row];
  }
}

// bf16 MFMA GEMM (64x64 tile, global_load_lds staging):
// MODE 0: fp32 out, 1: fp32 out + add, 2: gelu -> bf16 out, 3: bf16 out
template<int MODE>
__global__ __launch_bounds__(256) void k_bgemm(const __bf16* __restrict__ A, const __bf16* __restrict__ Bt,
                       const float* __restrict__ bias, const float* __restrict__ add,
                       float* __restrict__ outf, __bf16* __restrict__ outb,
                       int M, int N, int K){
  __shared__ __bf16 As[64*64];
  __shared__ __bf16 Bs[64*64];
  const int tid = threadIdx.x;
  const int lane = tid & 63;
  const int w = tid >> 6;
  const int wr = w >> 1, wc = w & 1;
  const int l15 = lane & 15, g = lane >> 4;
  const int bm = blockIdx.y*64, bn = blockIdx.x*64;
  f32x4 acc[2][2] = {};
  for(int k0=0; k0<K; k0+=64){
    #pragma unroll
    for(int rep=0; rep<2; rep++){
      int q = tid + rep*256;
      int row = q>>3;
      int scb = ((q&7)*16) ^ ((row&7)<<4);
      const __bf16* srcA = A  + (size_t)(bm+row)*K + k0 + (scb>>1);
      const __bf16* srcB = Bt + (size_t)(bn+row)*K + k0 + (scb>>1);
      __builtin_amdgcn_global_load_lds(
        (const __attribute__((address_space(1))) void*)srcA,
        (__attribute__((address_space(3))) void*)((char*)As + q*16), 16, 0, 0);
      __builtin_amdgcn_global_load_lds(
        (const __attribute__((address_space(1))) void*)srcB,
        (__attribute__((address_space(3))) void*)((char*)Bs + q*16), 16, 0, 0);
    }
    __syncthreads();
    #pragma unroll
    for(int ks=0; ks<2; ks++){
      bf16x8 a[2], b[2];
      #pragma unroll
      for(int i=0;i<2;i++){
        int row = wr*32 + i*16 + l15;
        int byte_ = row*128 + ks*64 + g*16; byte_ ^= (row&7)<<4;
        a[i] = *(const bf16x8*)((const char*)As + byte_);
      }
      #pragma unroll
      for(int j=0;j<2;j++){
        int row = wc*32 + j*16 + l15;
        int byte_ = row*128 + ks*64 + g*16; byte_ ^= (row&7)<<4;
        b[j] = *(const bf16x8*)((const char*)Bs + byte_);
      }
      #pragma unroll
      for(int i=0;i<2;i++)
        #pragma unroll
        for(int j=0;j<2;j++)
          acc[i][j] = __builtin_amdgcn_mfma_f32_16x16x32_bf16(a[i], b[j], acc[i][j], 0, 0, 0);
    }
    __syncthreads();
  }
  #pragma unroll
  for(int i=0;i<2;i++){
    #pragma unroll
    for(int j=0;j<2;j++){
      int col = bn + wc*32 + j*16 + l15;
      float bv = bias[col];
      #pragma unroll
      for(int r=0;r<4;r++){
        int rowg = bm + wr*32 + i*16 + g*4 + r;
        float v = acc[i][j][r] + bv;
        if(MODE==1) v += add[(size_t)rowg*N + col];
        if(MODE==2){
          v = 0.5f*v*(1.0f + erff(v*0.70710678118654752f));
          outb[(size_t)rowg*N + col] = (__bf16)v;
        } else if(MODE==3){
          outb[(size_t)rowg*N + col] = (__bf16)v;
        } else {
          outf[(size_t)rowg*N + col] = v;
        }
      }
    }
  }
}

// Fused Wo-GEMM + residual + LN2: block owns 16 FULL rows (N=256), 4 waves =
// 4 col-chunks. Writes hbuf (fp32, FF2 residual) and hn (bf16, LN2 output).
__global__ __launch_bounds__(256) void k_wln(const __bf16* __restrict__ A, const __bf16* __restrict__ Bt,
                    const float* __restrict__ bias, const float* __restrict__ add,
                    const float* __restrict__ g2, const float* __restrict__ be2,
                    float* __restrict__ hbuf, __bf16* __restrict__ hn){
  __shared__ __bf16 As[16*64];    // 2KB
  __shared__ __bf16 Bs[256*64];   // 32KB
  __shared__ float partS[64], partQ[64], muv[16], invv[16];
  const int tid = threadIdx.x;
  const int lane = tid & 63;
  const int w = tid >> 6;
  const int l15 = lane & 15, g = lane >> 4;
  const int bm = blockIdx.x*16;
  const int K = 256, N = 256;
  f32x4 acc[4] = {};
  for(int k0=0; k0<K; k0+=64){
    if(tid < 128){
      int q = tid;
      int row = q>>3;
      int scb = ((q&7)*16) ^ ((row&7)<<4);
      const __bf16* srcA = A + (size_t)(bm+row)*K + k0 + (scb>>1);
      __builtin_amdgcn_global_load_lds(
        (const __attribute__((address_space(1))) void*)srcA,
        (__attribute__((address_space(3))) void*)((char*)As + q*16), 16, 0, 0);
    }
    #pragma unroll
    for(int rep=0; rep<8; rep++){
      int q = tid + rep*256;
      int row = q>>3;
      int scb = ((q&7)*16) ^ ((row&7)<<4);
      const __bf16* srcB = Bt + (size_t)row*K + k0 + (scb>>1);
      __builtin_amdgcn_global_load_lds(
        (const __attribute__((address_space(1))) void*)srcB,
        (__attribute__((address_space(3))) void*)((char*)Bs + q*16), 16, 0, 0);
    }
    __syncthreads();
    #pragma unroll
    for(int ks=0; ks<2; ks++){
      bf16x8 a, b[4];
      { int row = l15;
        int byte_ = row*128 + ks*64 + g*16; byte_ ^= (row&7)<<4;
        a = *(const bf16x8*)((const char*)As + byte_); }
      #pragma unroll
      for(int j=0;j<4;j++){
        int row = w*64 + j*16 + l15;
        int byte_ = row*128 + ks*64 + g*16; byte_ ^= (row&7)<<4;
        b[j] = *(const bf16x8*)((const char*)Bs + byte_);
      }
      #pragma unroll
      for(int j=0;j<4;j++)
        acc[j] = __builtin_amdgcn_mfma_f32_16x16x32_bf16(a, b[j], acc[j], 0, 0, 0);
    }
    __syncthreads();
  }
  float v[4][4];
  #pragma unroll
  for(int j=0;j<4;j++){
    int col = w*64 + j*16 + l15;
    float bv = bias[col];
    #pragma unroll
    for(int r=0;r<4;r++){
      int rowg = bm + g*4 + r;
      v[j][r] = acc[j][r] + bv + add[(size_t)rowg*N + col];
    }
  }
  float s[4], qq[4];
  #pragma unroll
  for(int r=0;r<4;r++){
    s[r] = v[0][r]+v[1][r]+v[2][r]+v[3][r];
    qq[r] = v[0][r]*v[0][r]+v[1][r]*v[1][r]+v[2][r]*v[2][r]+v[3][r]*v[3][r];
  }
  #pragma unroll
  for(int m=8;m>=1;m>>=1){
    #pragma unroll
    for(int r=0;r<4;r++){ s[r] += __shfl_xor(s[r],m); qq[r] += __shfl_xor(qq[r],m); }
  }
  if(l15==0){
    #pragma unroll
    for(int r=0;r<4;r++){ partS[w*16 + g*4 + r] = s[r]; partQ[w*16 + g*4 + r] = qq[r]; }
  }
  __syncthreads();
  if(tid < 16){
    float S = partS[tid] + partS[16+tid] + partS[32+tid] + partS[48+tid];
    float Q = partQ[tid] + partQ[16+tid] + partQ[32+tid] + partQ[48+tid];
    float mu = S * (1.0f/256.0f);
    float var = Q * (1.0f/256.0f) - mu*mu;
    muv[tid] = mu;
    invv[tid] = rsqrtf(var + 1e-5f);
  }
  __syncthreads();
  #pragma unroll
  for(int j=0;j<4;j++){
    int col = w*64 + j*16 + l15;
    float gv = g2[col], bev = be2[col];
    #pragma unroll
    for(int r=0;r<4;r++){
      int rowg = bm + g*4 + r;
      float mu = muv[g*4+r], iv = invv[g*4+r];
      hbuf[(size_t)rowg*N + col] = v[j][r];
      hn[(size_t)rowg*N + col] = (__bf16)(gv*(v[j][r]-mu)*iv + bev);
    }
  }
}

// merged dispatch: blocks [0,2048) = prop F1->F2 (2 rows each, 256 thr);
// blocks [2048,2816) = QKV GEMM tiles (bf16 out, N=768, K=256).
__global__ __launch_bounds__(256) void k_pq(const int* __restrict__ cursor, const int* __restrict__ nsrc,
                    const unsigned* __restrict__ F1, unsigned* __restrict__ F2,
                    const __bf16* __restrict__ A, const __bf16* __restrict__ Bt,
                    const float* __restrict__ bias, __bf16* __restrict__ outb){
  __shared__ __bf16 As[64*64];
  __shared__ __bf16 Bs[64*64];
  const int b = blockIdx.x;
  const int tid = threadIdx.x;
  if(b < 2048){
    int d = b*2 + (tid>>7);
    int w_ = tid & 127;
    int cdeg = cursor[d]; if(cdeg > MAXD) cdeg = MAXD;
    const int* row = nsrc + d*MAXD;
    unsigned v = 0;
    for(int i=0;i<cdeg;i++) v |= F1[(size_t)row[i]*FW + w_];
    F2[(size_t)d*FW + w_] = v;
    return;
  }
  const int bx = b - 2048;
  const int N = 768, K = 256;
  const int bm = (bx/12)*64, bn = (bx%12)*64;
  const int lane = tid & 63;
  const int w = tid >> 6;
  const int wr = w >> 1, wc = w & 1;
  const int l15 = lane & 15, g = lane >> 4;
  f32x4 acc[2][2] = {};
  for(int k0=0; k0<K; k0+=64){
    #pragma unroll
    for(int rep=0; rep<2; rep++){
      int q = tid + rep*256;
      int row = q>>3;
      int scb = ((q&7)*16) ^ ((row&7)<<4);
      const __bf16* srcA = A  + (size_t)(bm+row)*K + k0 + (scb>>1);
      const __bf16* srcB = Bt + (size_t)(bn+row)*K + k0 + (scb>>1);
      __builtin_amdgcn_global_load_lds(
        (const __attribute__((address_space(1))) void*)srcA,
        (__attribute__((address_space(3))) void*)((char*)As + q*16), 16, 0, 0);
      __builtin_amdgcn_global_load_lds(
        (const __attribute__((address_space(1))) void*)srcB,
        (__attribute__((address_space(3))) void*)((char*)Bs + q*16), 16, 0, 0);
    }
    __syncthreads();
    #pragma unroll
    for(int ks=0; ks<2; ks++){
      bf16x8 a[2], bb[2];
      #pragma unroll
      for(int i=0;i<2;i++){
        int row = wr*32 + i*16 + l15;
        int byte_ = row*128 + ks*64 + g*16; byte_ ^= (row&7)<<4;
        a[i] = *(const bf16x8*)((const char*)As + byte_);
      }
      #pragma unroll
      for(int j=0;j<2;j++){
        int row = wc*32 + j*16 + l15;
        int byte_ = row*128 + ks*64 + g*16; byte_ ^= (row&7)<<4;
        bb[j] = *(const bf16x8*)((const char*)Bs + byte_);
      }
      #pragma unroll
      for(int i=0;i<2;i++)
        #pragma unroll
        for(int j=0;j<2;j++)
          acc[i][j] = __builtin_amdgcn_mfma_f32_16x16x32_bf16(a[i], bb[j], acc[i][j], 0, 0, 0);
    }
    __syncthreads();
  }
  #pragma unroll
  for(int i=0;i<2;i++){
    #pragma unroll
    for(int j=0;j<2;j++){
      int col = bn + wc*32 + j*16 + l15;
      float bv = bias[col];
      #pragma unroll
      for(int r=0;r<4;r++){
        int rowg = bm + wr*32 + i*16 + g*4 + r;
        outb[(size_t)rowg*N + col] = (__bf16)(acc[i][j][r] + bv);
      }
    }
  }
}

// Fused scores + segment softmax + V-aggregation. spd probe is lazy:
// spd3 probed via in-neighbors' F2 rows (F3[s] bit d == OR_m F2[m] bit d),
// so F3 is never materialized.
__global__ void k_sagg(const int* __restrict__ nsrc, const int* __restrict__ cursor,
                       const __bf16* __restrict__ QKV,
                       const unsigned* __restrict__ F1, const unsigned* __restrict__ F2,
                       const float* __restrict__ spde, __bf16* __restrict__ msg){
  __shared__ float scs[MAXD][9];
  __shared__ int   sl[MAXD];
  __shared__ int   spi[MAXD];
  const int d = blockIdx.x;
  const int t = threadIdx.x;
  int deg = cursor[d]; if(deg > MAXD) deg = MAXD;
  if(t < deg){
    int s = nsrc[d*MAXD+t];
    sl[t] = s;
    const int wo = d>>5; const unsigned bb = 1u << (d&31);
    int sp;
    if(F1[(size_t)s*FW + wo] & bb) sp = 1;
    else if(F2[(size_t)s*FW + wo] & bb) sp = 2;
    else {
      sp = 4;
      int sdeg = cursor[s]; if(sdeg > MAXD) sdeg = MAXD;
      const int* srow = nsrc + s*MAXD;
      for(int i=0;i<sdeg;i++){
        if(F2[(size_t)srow[i]*FW + wo] & bb){ sp = 3; break; }
      }
    }
    spi[t] = sp;
  }
  __syncthreads();
  // phase 1: (edge, head, quarter)-parallel scores
  { const int i0 = t>>5, h = (t>>2)&7, q = t&3;
    bf16x8 qv = *(const bf16x8*)(QKV + (size_t)d*768 + h*DHD + q*8);
    for(int i=i0; i<deg; i+=8){
      bf16x8 kv = *(const bf16x8*)(QKV + (size_t)sl[i]*768 + 256 + h*DHD + q*8);
      float p = 0.f;
      #pragma unroll
      for(int u=0;u<8;u++) p += (float)qv[u] * (float)kv[u];
      p += __shfl_xor(p,1);
      p += __shfl_xor(p,2);
      if(q==0) scs[i][h] = p * 0.17677669529663687f + spde[spi[i]*HH + h];
    }
  }
  __syncthreads();
  // phase 2: segment softmax per head
  { const int h = t >> 5, l = t & 31;
    float m = -3.0e38f;
    for(int i=l;i<deg;i+=32) m = fmaxf(m, scs[i][h]);
    #pragma unroll
    for(int mk=16;mk>=1;mk>>=1) m = fmaxf(m, __shfl_xor(m,mk));
    float ss = 0.f;
    for(int i=l;i<deg;i+=32) ss += expf(scs[i][h]-m);
    #pragma unroll
    for(int mk=16;mk>=1;mk>>=1) ss += __shfl_xor(ss,mk);
    float inv = (ss>0.f) ? 1.f/ss : 1.f;
    for(int i=l;i<deg;i+=32) scs[i][h] = expf(scs[i][h]-m)*inv;
  }
  __syncthreads();
  // phase 3: V aggregation
  { const int h = t >> 5, c = t & 31;
    float acc = 0.f;
    for(int i=0;i<deg;i++)
      acc += scs[i][h] * (float)QKV[(size_t)sl[i]*768 + 512 + h*DHD + c];
    msg[(size_t)d*CC + h*DHD + c] = (__bf16)acc;
  }
}

extern "C" void kernel_launch(void* const* d_in, const int* in_sizes, int n_in,
                              void* d_out, int out_size, void* d_ws, size_t ws_size,
                              hipStream_t stream){
  const float* x  = (const float*)d_in[0];
  const int*  ei  = (const int*)d_in[1];
  const float* Wq = (const float*)d_in[2];  const float* bq = (const float*)d_in[3];
  const float* Wk = (const float*)d_in[4];  const float* bk = (const float*)d_in[5];
  const float* Wv = (const float*)d_in[6];  const float* bv = (const float*)d_in[7];
  const float* Wo = (const float*)d_in[8];  const float* bo = (const float*)d_in[9];
  const float* W1 = (const float*)d_in[10]; const float* b1 = (const float*)d_in[11];
  const float* W2 = (const float*)d_in[12]; const float* b2 = (const float*)d_in[13];
  const float* g1 = (const float*)d_in[14]; const float* be1= (const float*)d_in[15];
  const float* g2 = (const float*)d_in[16]; const float* be2= (const float*)d_in[17];
  const float* spde = (const float*)d_in[18];
  const float* iemb = (const float*)d_in[19];
  const float* oemb = (const float*)d_in[20];
  const float* etb  = (const float*)d_in[21]; (void)etb; // cancels in softmax
  const int* src = ei;
  const int* dst = ei + EE;
  float* out = (float*)d_out;

  const size_t NC = (size_t)NN*CC;       // 1,048,576 floats
  float* ws   = (float*)d_ws;
  // ---- layout in float words ----
  float* x_in = ws;                                   // [0, NC)
  float* hbuf = ws + NC;                              // [NC, 2NC)
  int* cursor = (int*)(ws + 2*NC);                    // NN ints (= indeg)
  int* outdeg = cursor + NN;                          // NN ints
  unsigned* F1 = (unsigned*)(ws + 2*NC + 12288);
  unsigned* F2 = F1 + (size_t)NN*FW;                  // (F3 region now unused)
  __bf16* QKV  = (__bf16*)(ws + 3682304);             // [3,682,304 , 5,255,168)
  int* nsrc    = (int*)(ws + 5255168);                // NN*MAXD = 262,144 ints
  __bf16* xn_bf  = (__bf16*)(ws + 5517312);           // 262,144 words
  __bf16* msg_bf = (__bf16*)(ws + 6041600);           // 262,144 words
  __bf16* WqkvT  = (__bf16*)(ws + 6565888);           // 98,304 words
  __bf16* WoT    = WqkvT + 196608;
  __bf16* W1T    = WoT + 65536;
  __bf16* W2T    = W1T + 262144;                      // ends 6,959,104
  float* bqkv    = ws + 6959104;                      // 768
  // late-phase reuse (dead regions after sagg):
  __bf16* ff1_bf = (__bf16*)(ws + 2*NC);              // [2NC,4NC) over cursor/outdeg/F1-F2
  __bf16* hn_bf  = (__bf16*)(ws + 4*NC);              // [4NC,4.5NC) over QKV head

  // 1: weight prep + zero cursor|outdeg
  k_pre<<<225,256,0,stream>>>(Wq,Wk,Wv,Wo,W1,W2,bq,bk,bv,WqkvT,WoT,W1T,W2T,bqkv,cursor);
  // 2: single-pass degree count + fixed-slot CSR scatter
  k_scatter<<<EE/256,256,0,stream>>>(src,dst,cursor,outdeg,nsrc);
  // 3: F1 build + x_in/LN1
  k_mid<<<3072,256,0,stream>>>(cursor,nsrc,F1,x,outdeg,iemb,oemb,g1,be1,x_in,xn_bf);
  // 4: merged prop F1->F2 + QKV GEMM
  k_pq<<<2816,256,0,stream>>>(cursor,nsrc,F1,F2,xn_bf,WqkvT,bqkv,QKV);
  // 5: fused attention (spd3 probed lazily via in-neighbor F2 rows)
  k_sagg<<<NN,256,0,stream>>>(nsrc,cursor,QKV,F1,F2,spde,msg_bf);
  // 6: fused Wo-GEMM + residual + LN2
  k_wln<<<NN/16,256,0,stream>>>(msg_bf, WoT, bo, x_in, g2, be2, hbuf, hn_bf);
  // 7-8: FFN
  dim3 gf1(1024/64, NN/64);
  k_bgemm<2><<<gf1,256,0,stream>>>(hn_bf, W1T, b1, nullptr, nullptr, ff1_bf, NN, 1024, 256);
  dim3 gf2(256/64, NN/64);
  k_bgemm<1><<<gf2,256,0,stream>>>(ff1_bf, W2T, b2, hbuf, out, nullptr, NN, 256, 1024);
}

// Round 16
// 79.277 us; speedup vs baseline: 1.1458x; 1.1458x over previous
//
#include <hip/hip_runtime.h>
#include <math.h>

#define NN 4096
#define CC 256
#define HH 8
#define DHD 32
#define EE 32768
#define FW 128   // bitset words per row (4096/32)
#define MAXD 64  // fixed CSR slots per dst (Poisson(8): P(deg>64) ~ 1e-35)

typedef float f32x4 __attribute__((ext_vector_type(4)));
typedef __bf16 bf16x8 __attribute__((ext_vector_type(8)));
typedef __bf16 bf16x4 __attribute__((ext_vector_type(4)));

__device__ __forceinline__ int bucketf(int d){
  float l = log2f((float)d + 1.0f);
  int b = (int)floorf(l);
  return b < 0 ? 0 : (b > 8 ? 8 : b);
}

// single pass: outdeg + cursor(=indeg) atomics + fixed-slot CSR scatter
__global__ void k_scatter(const int* __restrict__ src, const int* __restrict__ dst,
                          int* __restrict__ cursor, int* __restrict__ outdeg,
                          int* __restrict__ nsrc){
  int e = blockIdx.x*256+threadIdx.x;
  if(e<EE){
    int d = dst[e], s = src[e];
    atomicAdd(&outdeg[s],1);
    int p = atomicAdd(&cursor[d],1);
    if(p < MAXD) nsrc[d*MAXD+p] = s;
  }
}

// merged: blocks [0,2048) build F1 (2 rows each); blocks [2048,3072) do
// x_in = x + deg embeds ; xn = LN1(x_in) (4 nodes each).
__global__ void k_mid(const int* __restrict__ cursor, const int* __restrict__ nsrc,
                      unsigned* __restrict__ F1,
                      const float* __restrict__ x,
                      const int* __restrict__ outdeg, const float* __restrict__ iemb,
                      const float* __restrict__ oemb, const float* __restrict__ g,
                      const float* __restrict__ be, float* __restrict__ x_in,
                      __bf16* __restrict__ xn){
  int b = blockIdx.x;
  int tid = threadIdx.x;
  if(b < 2048){
    int d = b*2 + (tid>>7);
    int w = tid & 127;
    int cdeg = cursor[d]; if(cdeg > MAXD) cdeg = MAXD;
    const int* row = nsrc + d*MAXD;
    unsigned v = 0;
    for(int i=0;i<cdeg;i++){
      int s = row[i];
      if((s>>5) == w) v |= 1u << (s&31);
    }
    F1[(size_t)d*FW + w] = v;
    return;
  }
  int node = (b-2048)*4 + (tid >> 6);
  int lane = tid & 63;
  int bi = bucketf(cursor[node]);   // cursor = true indeg (uncapped count)
  int bo = bucketf(outdeg[node]);
  float4 xv = ((const float4*)(x + (size_t)node*CC))[lane];
  float4 iv = ((const float4*)(iemb + (size_t)bi*CC))[lane];
  float4 ov = ((const float4*)(oemb + (size_t)bo*CC))[lane];
  float4 v;
  v.x = xv.x+iv.x+ov.x; v.y = xv.y+iv.y+ov.y;
  v.z = xv.z+iv.z+ov.z; v.w = xv.w+iv.w+ov.w;
  ((float4*)(x_in + (size_t)node*CC))[lane] = v;
  float s  = v.x+v.y+v.z+v.w;
  float sq = v.x*v.x+v.y*v.y+v.z*v.z+v.w*v.w;
  #pragma unroll
  for(int m=32;m>=1;m>>=1){ s += __shfl_xor(s,m); sq += __shfl_xor(sq,m); }
  float mu  = s * (1.0f/CC);
  float var = sq * (1.0f/CC) - mu*mu;
  float inv = rsqrtf(var + 1e-5f);
  float4 gv = ((const float4*)g)[lane];
  float4 bv = ((const float4*)be)[lane];
  bf16x4 o;
  o[0] = (__bf16)(gv.x*(v.x-mu)*inv + bv.x);
  o[1] = (__bf16)(gv.y*(v.y-mu)*inv + bv.y);
  o[2] = (__bf16)(gv.z*(v.z-mu)*inv + bv.z);
  o[3] = (__bf16)(gv.w*(v.w-mu)*inv + bv.w);
  *(bf16x4*)(xn + (size_t)node*CC + lane*4) = o;
}

// weight transposes (fp32 [K,N] -> bf16 [N,K]) + qkv bias concat + counter zero.
__global__ void k_pre(const float* __restrict__ Wq, const float* __restrict__ Wk,
                      const float* __restrict__ Wv, const float* __restrict__ Wo,
                      const float* __restrict__ W1, const float* __restrict__ W2,
                      const float* __restrict__ bq, const float* __restrict__ bk,
                      const float* __restrict__ bv,
                      __bf16* __restrict__ WqkvT, __bf16* __restrict__ WoT,
                      __bf16* __restrict__ W1T, __bf16* __restrict__ W2T,
                      float* __restrict__ bqkv, int* __restrict__ zero_base){
  int b = blockIdx.x;
  int tid = threadIdx.x;
  if(b >= 193){
    zero_base[(b-193)*256 + tid] = 0;   // cursor|outdeg = 8192 ints
    return;
  }
  if(b == 192){
    bqkv[tid]     = bq[tid];
    bqkv[256+tid] = bk[tid];
    bqkv[512+tid] = bv[tid];
    return;
  }
  const float* W; __bf16* Wt; int K, N, tile;
  if(b < 16)      { W=Wq; Wt=WqkvT;        K=256;  N=256;  tile=b; }
  else if(b < 32) { W=Wk; Wt=WqkvT+65536;  K=256;  N=256;  tile=b-16; }
  else if(b < 48) { W=Wv; Wt=WqkvT+131072; K=256;  N=256;  tile=b-32; }
  else if(b < 64) { W=Wo; Wt=WoT;          K=256;  N=256;  tile=b-48; }
  else if(b < 128){ W=W1; Wt=W1T;          K=256;  N=1024; tile=b-64; }
  else            { W=W2; Wt=W2T;          K=1024; N=256;  tile=b-128; }
  int nK = K/64;
  int tk = tile % nK, tn = tile / nK;
  __shared__ float T[64][65];
  int c = tid & 63, r0 = tid >> 6;
  #pragma unroll
  for(int i=0;i<16;i++){
    int row = r0*16 + i;
    T[row][c] = W[(size_t)(tk*64+row)*N + tn*64 + c];
  }
  __syncthreads();
  #pragma unroll
  for(int i=0;i<16;i++){
    int row = r0*16 + i;
    Wt[(size_t)(tn*64+row)*K + tk*64 + c] = (__bf16)T[c][row];
  }
}

// bf16 MFMA GEMM (64x64 tile, global_load_lds staging):
// MODE 0: fp32 out, 1: fp32 out + add, 2: gelu -> bf16 out, 3: bf16 out
template<int MODE>
__global__ __launch_bounds__(256) void k_bgemm(const __bf16* __restrict__ A, const __bf16* __restrict__ Bt,
                       const float* __restrict__ bias, const float* __restrict__ add,
                       float* __restrict__ outf, __bf16* __restrict__ outb,
                       int M, int N, int K){
  __shared__ __bf16 As[64*64];
  __shared__ __bf16 Bs[64*64];
  const int tid = threadIdx.x;
  const int lane = tid & 63;
  const int w = tid >> 6;
  const int wr = w >> 1, wc = w & 1;
  const int l15 = lane & 15, g = lane >> 4;
  const int bm = blockIdx.y*64, bn = blockIdx.x*64;
  f32x4 acc[2][2] = {};
  for(int k0=0; k0<K; k0+=64){
    #pragma unroll
    for(int rep=0; rep<2; rep++){
      int q = tid + rep*256;
      int row = q>>3;
      int scb = ((q&7)*16) ^ ((row&7)<<4);
      const __bf16* srcA = A  + (size_t)(bm+row)*K + k0 + (scb>>1);
      const __bf16* srcB = Bt + (size_t)(bn+row)*K + k0 + (scb>>1);
      __builtin_amdgcn_global_load_lds(
        (const __attribute__((address_space(1))) void*)srcA,
        (__attribute__((address_space(3))) void*)((char*)As + q*16), 16, 0, 0);
      __builtin_amdgcn_global_load_lds(
        (const __attribute__((address_space(1))) void*)srcB,
        (__attribute__((address_space(3))) void*)((char*)Bs + q*16), 16, 0, 0);
    }
    __syncthreads();
    #pragma unroll
    for(int ks=0; ks<2; ks++){
      bf16x8 a[2], b[2];
      #pragma unroll
      for(int i=0;i<2;i++){
        int row = wr*32 + i*16 + l15;
        int byte_ = row*128 + ks*64 + g*16; byte_ ^= (row&7)<<4;
        a[i] = *(const bf16x8*)((const char*)As + byte_);
      }
      #pragma unroll
      for(int j=0;j<2;j++){
        int row = wc*32 + j*16 + l15;
        int byte_ = row*128 + ks*64 + g*16; byte_ ^= (row&7)<<4;
        b[j] = *(const bf16x8*)((const char*)Bs + byte_);
      }
      #pragma unroll
      for(int i=0;i<2;i++)
        #pragma unroll
        for(int j=0;j<2;j++)
          acc[i][j] = __builtin_amdgcn_mfma_f32_16x16x32_bf16(a[i], b[j], acc[i][j], 0, 0, 0);
    }
    __syncthreads();
  }
  #pragma unroll
  for(int i=0;i<2;i++){
    #pragma unroll
    for(int j=0;j<2;j++){
      int col = bn + wc*32 + j*16 + l15;
      float bv = bias[col];
      #pragma unroll
      for(int r=0;r<4;r++){
        int rowg = bm + wr*32 + i*16 + g*4 + r;
        float v = acc[i][j][r] + bv;
        if(MODE==1) v += add[(size_t)rowg*N + col];
        if(MODE==2){
          v = 0.5f*v*(1.0f + erff(v*0.70710678118654752f));
          outb[(size_t)rowg*N + col] = (__bf16)v;
        } else if(MODE==3){
          outb[(size_t)rowg*N + col] = (__bf16)v;
        } else {
          outf[(size_t)rowg*N + col] = v;
        }
      }
    }
  }
}

// Fused Wo-GEMM + residual + LN2: block owns 16 FULL rows (N=256), 4 waves =
// 4 col-chunks. Writes hbuf (fp32, FF2 residual) and hn (bf16, LN2 output).
__global__ __launch_bounds__(256) void k_wln(const __bf16* __restrict__ A, const __bf16* __restrict__ Bt,
                    const float* __restrict__ bias, const float* __restrict__ add,
                    const float* __restrict__ g2, const float* __restrict__ be2,
                    float* __restrict__ hbuf, __bf16* __restrict__ hn){
  __shared__ __bf16 As[16*64];    // 2KB
  __shared__ __bf16 Bs[256*64];   // 32KB
  __shared__ float partS[64], partQ[64], muv[16], invv[16];
  const int tid = threadIdx.x;
  const int lane = tid & 63;
  const int w = tid >> 6;
  const int l15 = lane & 15, g = lane >> 4;
  const int bm = blockIdx.x*16;
  const int K = 256, N = 256;
  f32x4 acc[4] = {};
  for(int k0=0; k0<K; k0+=64){
    if(tid < 128){
      int q = tid;
      int row = q>>3;
      int scb = ((q&7)*16) ^ ((row&7)<<4);
      const __bf16* srcA = A + (size_t)(bm+row)*K + k0 + (scb>>1);
      __builtin_amdgcn_global_load_lds(
        (const __attribute__((address_space(1))) void*)srcA,
        (__attribute__((address_space(3))) void*)((char*)As + q*16), 16, 0, 0);
    }
    #pragma unroll
    for(int rep=0; rep<8; rep++){
      int q = tid + rep*256;
      int row = q>>3;
      int scb = ((q&7)*16) ^ ((row&7)<<4);
      const __bf16* srcB = Bt + (size_t)row*K + k0 + (scb>>1);
      __builtin_amdgcn_global_load_lds(
        (const __attribute__((address_space(1))) void*)srcB,
        (__attribute__((address_space(3))) void*)((char*)Bs + q*16), 16, 0, 0);
    }
    __syncthreads();
    #pragma unroll
    for(int ks=0; ks<2; ks++){
      bf16x8 a, b[4];
      { int row = l15;
        int byte_ = row*128 + ks*64 + g*16; byte_ ^= (row&7)<<4;
        a = *(const bf16x8*)((const char*)As + byte_); }
      #pragma unroll
      for(int j=0;j<4;j++){
        int row = w*64 + j*16 + l15;
        int byte_ = row*128 + ks*64 + g*16; byte_ ^= (row&7)<<4;
        b[j] = *(const bf16x8*)((const char*)Bs + byte_);
      }
      #pragma unroll
      for(int j=0;j<4;j++)
        acc[j] = __builtin_amdgcn_mfma_f32_16x16x32_bf16(a, b[j], acc[j], 0, 0, 0);
    }
    __syncthreads();
  }
  float v[4][4];
  #pragma unroll
  for(int j=0;j<4;j++){
    int col = w*64 + j*16 + l15;
    float bv = bias[col];
    #pragma unroll
    for(int r=0;r<4;r++){
      int rowg = bm + g*4 + r;
      v[j][r] = acc[j][r] + bv + add[(size_t)rowg*N + col];
    }
  }
  float s[4], qq[4];
  #pragma unroll
  for(int r=0;r<4;r++){
    s[r] = v[0][r]+v[1][r]+v[2][r]+v[3][r];
    qq[r] = v[0][r]*v[0][r]+v[1][r]*v[1][r]+v[2][r]*v[2][r]+v[3][r]*v[3][r];
  }
  #pragma unroll
  for(int m=8;m>=1;m>>=1){
    #pragma unroll
    for(int r=0;r<4;r++){ s[r] += __shfl_xor(s[r],m); qq[r] += __shfl_xor(qq[r],m); }
  }
  if(l15==0){
    #pragma unroll
    for(int r=0;r<4;r++){ partS[w*16 + g*4 + r] = s[r]; partQ[w*16 + g*4 + r] = qq[r]; }
  }
  __syncthreads();
  if(tid < 16){
    float S = partS[tid] + partS[16+tid] + partS[32+tid] + partS[48+tid];
    float Q = partQ[tid] + partQ[16+tid] + partQ[32+tid] + partQ[48+tid];
    float mu = S * (1.0f/256.0f);
    float var = Q * (1.0f/256.0f) - mu*mu;
    muv[tid] = mu;
    invv[tid] = rsqrtf(var + 1e-5f);
  }
  __syncthreads();
  #pragma unroll
  for(int j=0;j<4;j++){
    int col = w*64 + j*16 + l15;
    float gv = g2[col], bev = be2[col];
    #pragma unroll
    for(int r=0;r<4;r++){
      int rowg = bm + g*4 + r;
      float mu = muv[g*4+r], iv = invv[g*4+r];
      hbuf[(size_t)rowg*N + col] = v[j][r];
      hn[(size_t)rowg*N + col] = (__bf16)(gv*(v[j][r]-mu)*iv + bev);
    }
  }
}

// merged dispatch: blocks [0,2048) = prop F1->F2 (2 rows each, 256 thr);
// blocks [2048,2816) = QKV GEMM tiles (bf16 out, N=768, K=256).
__global__ __launch_bounds__(256) void k_pq(const int* __restrict__ cursor, const int* __restrict__ nsrc,
                    const unsigned* __restrict__ F1, unsigned* __restrict__ F2,
                    const __bf16* __restrict__ A, const __bf16* __restrict__ Bt,
                    const float* __restrict__ bias, __bf16* __restrict__ outb){
  __shared__ __bf16 As[64*64];
  __shared__ __bf16 Bs[64*64];
  const int b = blockIdx.x;
  const int tid = threadIdx.x;
  if(b < 2048){
    int d = b*2 + (tid>>7);
    int w_ = tid & 127;
    int cdeg = cursor[d]; if(cdeg > MAXD) cdeg = MAXD;
    const int* row = nsrc + d*MAXD;
    unsigned v = 0;
    for(int i=0;i<cdeg;i++) v |= F1[(size_t)row[i]*FW + w_];
    F2[(size_t)d*FW + w_] = v;
    return;
  }
  const int bx = b - 2048;
  const int N = 768, K = 256;
  const int bm = (bx/12)*64, bn = (bx%12)*64;
  const int lane = tid & 63;
  const int w = tid >> 6;
  const int wr = w >> 1, wc = w & 1;
  const int l15 = lane & 15, g = lane >> 4;
  f32x4 acc[2][2] = {};
  for(int k0=0; k0<K; k0+=64){
    #pragma unroll
    for(int rep=0; rep<2; rep++){
      int q = tid + rep*256;
      int row = q>>3;
      int scb = ((q&7)*16) ^ ((row&7)<<4);
      const __bf16* srcA = A  + (size_t)(bm+row)*K + k0 + (scb>>1);
      const __bf16* srcB = Bt + (size_t)(bn+row)*K + k0 + (scb>>1);
      __builtin_amdgcn_global_load_lds(
        (const __attribute__((address_space(1))) void*)srcA,
        (__attribute__((address_space(3))) void*)((char*)As + q*16), 16, 0, 0);
      __builtin_amdgcn_global_load_lds(
        (const __attribute__((address_space(1))) void*)srcB,
        (__attribute__((address_space(3))) void*)((char*)Bs + q*16), 16, 0, 0);
    }
    __syncthreads();
    #pragma unroll
    for(int ks=0; ks<2; ks++){
      bf16x8 a[2], bb[2];
      #pragma unroll
      for(int i=0;i<2;i++){
        int row = wr*32 + i*16 + l15;
        int byte_ = row*128 + ks*64 + g*16; byte_ ^= (row&7)<<4;
        a[i] = *(const bf16x8*)((const char*)As + byte_);
      }
      #pragma unroll
      for(int j=0;j<2;j++){
        int row = wc*32 + j*16 + l15;
        int byte_ = row*128 + ks*64 + g*16; byte_ ^= (row&7)<<4;
        bb[j] = *(const bf16x8*)((const char*)Bs + byte_);
      }
      #pragma unroll
      for(int i=0;i<2;i++)
        #pragma unroll
        for(int j=0;j<2;j++)
          acc[i][j] = __builtin_amdgcn_mfma_f32_16x16x32_bf16(a[i], bb[j], acc[i][j], 0, 0, 0);
    }
    __syncthreads();
  }
  #pragma unroll
  for(int i=0;i<2;i++){
    #pragma unroll
    for(int j=0;j<2;j++){
      int col = bn + wc*32 + j*16 + l15;
      float bv = bias[col];
      #pragma unroll
      for(int r=0;r<4;r++){
        int rowg = bm + wr*32 + i*16 + g*4 + r;
        outb[(size_t)rowg*N + col] = (__bf16)(acc[i][j][r] + bv);
      }
    }
  }
}

// Fused scores + segment softmax + V-aggregation. Lazy spd3 probe,
// PARALLELIZED: 8 threads per unresolved edge each check a subset of
// s's in-neighbors (independent loads, not a serial chain).
__global__ void k_sagg(const int* __restrict__ nsrc, const int* __restrict__ cursor,
                       const __bf16* __restrict__ QKV,
                       const unsigned* __restrict__ F1, const unsigned* __restrict__ F2,
                       const float* __restrict__ spde, __bf16* __restrict__ msg){
  __shared__ float scs[MAXD][9];
  __shared__ int   sl[MAXD];
  __shared__ int   spi[MAXD];
  const int d = blockIdx.x;
  const int t = threadIdx.x;
  const int wo = d>>5; const unsigned bb = 1u << (d&31);
  int deg = cursor[d]; if(deg > MAXD) deg = MAXD;
  if(t < deg){
    int s = nsrc[d*MAXD+t];
    sl[t] = s;
    int sp = 4;
    if(F1[(size_t)s*FW + wo] & bb) sp = 1;
    else if(F2[(size_t)s*FW + wo] & bb) sp = 2;
    spi[t] = sp;
  }
  __syncthreads();
  // parallel spd3 probe: edge i = t>>3 (stride 32), probe-lane j = t&7
  { const int j = t & 7;
    for(int i = t>>3; i < deg; i += 32){
      if(spi[i] == 4){
        int s = sl[i];
        int sdeg = cursor[s]; if(sdeg > MAXD) sdeg = MAXD;
        const int* srow = nsrc + s*MAXD;
        for(int k=j; k<sdeg; k+=8){
          if(F2[(size_t)srow[k]*FW + wo] & bb){ spi[i] = 3; break; }
        }
      }
    }
  }
  __syncthreads();
  // phase 1: (edge, head, quarter)-parallel scores
  { const int i0 = t>>5, h = (t>>2)&7, q = t&3;
    bf16x8 qv = *(const bf16x8*)(QKV + (size_t)d*768 + h*DHD + q*8);
    for(int i=i0; i<deg; i+=8){
      bf16x8 kv = *(const bf16x8*)(QKV + (size_t)sl[i]*768 + 256 + h*DHD + q*8);
      float p = 0.f;
      #pragma unroll
      for(int u=0;u<8;u++) p += (float)qv[u] * (float)kv[u];
      p += __shfl_xor(p,1);
      p += __shfl_xor(p,2);
      if(q==0) scs[i][h] = p * 0.17677669529663687f + spde[spi[i]*HH + h];
    }
  }
  __syncthreads();
  // phase 2: segment softmax per head
  { const int h = t >> 5, l = t & 31;
    float m = -3.0e38f;
    for(int i=l;i<deg;i+=32) m = fmaxf(m, scs[i][h]);
    #pragma unroll
    for(int mk=16;mk>=1;mk>>=1) m = fmaxf(m, __shfl_xor(m,mk));
    float ss = 0.f;
    for(int i=l;i<deg;i+=32) ss += expf(scs[i][h]-m);
    #pragma unroll
    for(int mk=16;mk>=1;mk>>=1) ss += __shfl_xor(ss,mk);
    float inv = (ss>0.f) ? 1.f/ss : 1.f;
    for(int i=l;i<deg;i+=32) scs[i][h] = expf(scs[i][h]-m)*inv;
  }
  __syncthreads();
  // phase 3: V aggregation
  { const int h = t >> 5, c = t & 31;
    float acc = 0.f;
    for(int i=0;i<deg;i++)
      acc += scs[i][h] * (float)QKV[(size_t)sl[i]*768 + 512 + h*DHD + c];
    msg[(size_t)d*CC + h*DHD + c] = (__bf16)acc;
  }
}

extern "C" void kernel_launch(void* const* d_in, const int* in_sizes, int n_in,
                              void* d_out, int out_size, void* d_ws, size_t ws_size,
                              hipStream_t stream){
  const float* x  = (const float*)d_in[0];
  const int*  ei  = (const int*)d_in[1];
  const float* Wq = (const float*)d_in[2];  const float* bq = (const float*)d_in[3];
  const float* Wk = (const float*)d_in[4];  const float* bk = (const float*)d_in[5];
  const float* Wv = (const float*)d_in[6];  const float* bv = (const float*)d_in[7];
  const float* Wo = (const float*)d_in[8];  const float* bo = (const float*)d_in[9];
  const float* W1 = (const float*)d_in[10]; const float* b1 = (const float*)d_in[11];
  const float* W2 = (const float*)d_in[12]; const float* b2 = (const float*)d_in[13];
  const float* g1 = (const float*)d_in[14]; const float* be1= (const float*)d_in[15];
  const float* g2 = (const float*)d_in[16]; const float* be2= (const float*)d_in[17];
  const float* spde = (const float*)d_in[18];
  const float* iemb = (const float*)d_in[19];
  const float* oemb = (const float*)d_in[20];
  const float* etb  = (const float*)d_in[21]; (void)etb; // cancels in softmax
  const int* src = ei;
  const int* dst = ei + EE;
  float* out = (float*)d_out;

  const size_t NC = (size_t)NN*CC;       // 1,048,576 floats
  float* ws   = (float*)d_ws;
  // ---- layout in float words ----
  float* x_in = ws;                                   // [0, NC)
  float* hbuf = ws + NC;                              // [NC, 2NC)
  int* cursor = (int*)(ws + 2*NC);                    // NN ints (= indeg)
  int* outdeg = cursor + NN;                          // NN ints
  unsigned* F1 = (unsigned*)(ws + 2*NC + 12288);
  unsigned* F2 = F1 + (size_t)NN*FW;                  // (F3 region unused)
  __bf16* QKV  = (__bf16*)(ws + 3682304);             // [3,682,304 , 5,255,168)
  int* nsrc    = (int*)(ws + 5255168);                // NN*MAXD = 262,144 ints
  __bf16* xn_bf  = (__bf16*)(ws + 5517312);           // 262,144 words
  __bf16* msg_bf = (__bf16*)(ws + 6041600);           // 262,144 words
  __bf16* WqkvT  = (__bf16*)(ws + 6565888);           // 98,304 words
  __bf16* WoT    = WqkvT + 196608;
  __bf16* W1T    = WoT + 65536;
  __bf16* W2T    = W1T + 262144;                      // ends 6,959,104
  float* bqkv    = ws + 6959104;                      // 768
  // late-phase reuse (dead regions after sagg):
  __bf16* ff1_bf = (__bf16*)(ws + 2*NC);              // [2NC,4NC) over cursor/outdeg/F1-F2
  __bf16* hn_bf  = (__bf16*)(ws + 4*NC);              // [4NC,4.5NC) over QKV head

  // 1: weight prep + zero cursor|outdeg
  k_pre<<<225,256,0,stream>>>(Wq,Wk,Wv,Wo,W1,W2,bq,bk,bv,WqkvT,WoT,W1T,W2T,bqkv,cursor);
  // 2: single-pass degree count + fixed-slot CSR scatter
  k_scatter<<<EE/256,256,0,stream>>>(src,dst,cursor,outdeg,nsrc);
  // 3: F1 build + x_in/LN1
  k_mid<<<3072,256,0,stream>>>(cursor,nsrc,F1,x,outdeg,iemb,oemb,g1,be1,x_in,xn_bf);
  // 4: merged prop F1->F2 + QKV GEMM
  k_pq<<<2816,256,0,stream>>>(cursor,nsrc,F1,F2,xn_bf,WqkvT,bqkv,QKV);
  // 5: fused attention (parallel lazy spd3 probe)
  k_sagg<<<NN,256,0,stream>>>(nsrc,cursor,QKV,F1,F2,spde,msg_bf);
  // 6: fused Wo-GEMM + residual + LN2
  k_wln<<<NN/16,256,0,stream>>>(msg_bf, WoT, bo, x_in, g2, be2, hbuf, hn_bf);
  // 7-8: FFN
  dim3 gf1(1024/64, NN/64);
  k_bgemm<2><<<gf1,256,0,stream>>>(hn_bf, W1T, b1, nullptr, nullptr, ff1_bf, NN, 1024, 256);
  dim3 gf2(256/64, NN/64);
  k_bgemm<1><<<gf2,256,0,stream>>>(ff1_bf, W2T, b2, hbuf, out, nullptr, NN, 256, 1024);
}

// Round 17
// 78.564 us; speedup vs baseline: 1.1563x; 1.0091x over previous
//
#include <hip/hip_runtime.h>
#include <math.h>

#define NN 4096
#define CC 256
#define HH 8
#define DHD 32
#define EE 32768
#define FW 128   // bitset words per row (4096/32)
#define MAXD 64  // fixed CSR slots per dst (Poisson(8): P(deg>64) ~ 1e-35)

typedef float f32x4 __attribute__((ext_vector_type(4)));
typedef __bf16 bf16x8 __attribute__((ext_vector_type(8)));
typedef __bf16 bf16x4 __attribute__((ext_vector_type(4)));

__device__ __forceinline__ int bucketf(int d){
  float l = log2f((float)d + 1.0f);
  int b = (int)floorf(l);
  return b < 0 ? 0 : (b > 8 ? 8 : b);
}

// single pass: outdeg + cursor(=indeg) atomics + fixed-slot CSR scatter
__global__ void k_scatter(const int* __restrict__ src, const int* __restrict__ dst,
                          int* __restrict__ cursor, int* __restrict__ outdeg,
                          int* __restrict__ nsrc){
  int e = blockIdx.x*256+threadIdx.x;
  if(e<EE){
    int d = dst[e], s = src[e];
    atomicAdd(&outdeg[s],1);
    int p = atomicAdd(&cursor[d],1);
    if(p < MAXD) nsrc[d*MAXD+p] = s;
  }
}

// merged: blocks [0,2048) build F1 (2 rows each); blocks [2048,3072) do
// x_in = x + deg embeds ; xn = LN1(x_in) (4 nodes each).
__global__ void k_mid(const int* __restrict__ cursor, const int* __restrict__ nsrc,
                      unsigned* __restrict__ F1,
                      const float* __restrict__ x,
                      const int* __restrict__ outdeg, const float* __restrict__ iemb,
                      const float* __restrict__ oemb, const float* __restrict__ g,
                      const float* __restrict__ be, float* __restrict__ x_in,
                      __bf16* __restrict__ xn){
  int b = blockIdx.x;
  int tid = threadIdx.x;
  if(b < 2048){
    int d = b*2 + (tid>>7);
    int w = tid & 127;
    int cdeg = cursor[d]; if(cdeg > MAXD) cdeg = MAXD;
    const int* row = nsrc + d*MAXD;
    unsigned v = 0;
    for(int i=0;i<cdeg;i++){
      int s = row[i];
      if((s>>5) == w) v |= 1u << (s&31);
    }
    F1[(size_t)d*FW + w] = v;
    return;
  }
  int node = (b-2048)*4 + (tid >> 6);
  int lane = tid & 63;
  int bi = bucketf(cursor[node]);   // cursor = true indeg (uncapped count)
  int bo = bucketf(outdeg[node]);
  float4 xv = ((const float4*)(x + (size_t)node*CC))[lane];
  float4 iv = ((const float4*)(iemb + (size_t)bi*CC))[lane];
  float4 ov = ((const float4*)(oemb + (size_t)bo*CC))[lane];
  float4 v;
  v.x = xv.x+iv.x+ov.x; v.y = xv.y+iv.y+ov.y;
  v.z = xv.z+iv.z+ov.z; v.w = xv.w+iv.w+ov.w;
  ((float4*)(x_in + (size_t)node*CC))[lane] = v;
  float s  = v.x+v.y+v.z+v.w;
  float sq = v.x*v.x+v.y*v.y+v.z*v.z+v.w*v.w;
  #pragma unroll
  for(int m=32;m>=1;m>>=1){ s += __shfl_xor(s,m); sq += __shfl_xor(sq,m); }
  float mu  = s * (1.0f/CC);
  float var = sq * (1.0f/CC) - mu*mu;
  float inv = rsqrtf(var + 1e-5f);
  float4 gv = ((const float4*)g)[lane];
  float4 bv = ((const float4*)be)[lane];
  bf16x4 o;
  o[0] = (__bf16)(gv.x*(v.x-mu)*inv + bv.x);
  o[1] = (__bf16)(gv.y*(v.y-mu)*inv + bv.y);
  o[2] = (__bf16)(gv.z*(v.z-mu)*inv + bv.z);
  o[3] = (__bf16)(gv.w*(v.w-mu)*inv + bv.w);
  *(bf16x4*)(xn + (size_t)node*CC + lane*4) = o;
}

// weight transposes (fp32 [K,N] -> bf16 [N,K]) + qkv bias concat + counter zero.
__global__ void k_pre(const float* __restrict__ Wq, const float* __restrict__ Wk,
                      const float* __restrict__ Wv, const float* __restrict__ Wo,
                      const float* __restrict__ W1, const float* __restrict__ W2,
                      const float* __restrict__ bq, const float* __restrict__ bk,
                      const float* __restrict__ bv,
                      __bf16* __restrict__ WqkvT, __bf16* __restrict__ WoT,
                      __bf16* __restrict__ W1T, __bf16* __restrict__ W2T,
                      float* __restrict__ bqkv, int* __restrict__ zero_base){
  int b = blockIdx.x;
  int tid = threadIdx.x;
  if(b >= 193){
    zero_base[(b-193)*256 + tid] = 0;   // cursor|outdeg = 8192 ints
    return;
  }
  if(b == 192){
    bqkv[tid]     = bq[tid];
    bqkv[256+tid] = bk[tid];
    bqkv[512+tid] = bv[tid];
    return;
  }
  const float* W; __bf16* Wt; int K, N, tile;
  if(b < 16)      { W=Wq; Wt=WqkvT;        K=256;  N=256;  tile=b; }
  else if(b < 32) { W=Wk; Wt=WqkvT+65536;  K=256;  N=256;  tile=b-16; }
  else if(b < 48) { W=Wv; Wt=WqkvT+131072; K=256;  N=256;  tile=b-32; }
  else if(b < 64) { W=Wo; Wt=WoT;          K=256;  N=256;  tile=b-48; }
  else if(b < 128){ W=W1; Wt=W1T;          K=256;  N=1024; tile=b-64; }
  else            { W=W2; Wt=W2T;          K=1024; N=256;  tile=b-128; }
  int nK = K/64;
  int tk = tile % nK, tn = tile / nK;
  __shared__ float T[64][65];
  int c = tid & 63, r0 = tid >> 6;
  #pragma unroll
  for(int i=0;i<16;i++){
    int row = r0*16 + i;
    T[row][c] = W[(size_t)(tk*64+row)*N + tn*64 + c];
  }
  __syncthreads();
  #pragma unroll
  for(int i=0;i<16;i++){
    int row = r0*16 + i;
    Wt[(size_t)(tn*64+row)*K + tk*64 + c] = (__bf16)T[c][row];
  }
}

// bf16 MFMA GEMM (64x64 tile, global_load_lds staging):
// MODE 0: fp32 out, 1: fp32 out + add, 2: gelu -> bf16 out, 3: bf16 out
template<int MODE>
__global__ __launch_bounds__(256) void k_bgemm(const __bf16* __restrict__ A, const __bf16* __restrict__ Bt,
                       const float* __restrict__ bias, const float* __restrict__ add,
                       float* __restrict__ outf, __bf16* __restrict__ outb,
                       int M, int N, int K){
  __shared__ __bf16 As[64*64];
  __shared__ __bf16 Bs[64*64];
  const int tid = threadIdx.x;
  const int lane = tid & 63;
  const int w = tid >> 6;
  const int wr = w >> 1, wc = w & 1;
  const int l15 = lane & 15, g = lane >> 4;
  const int bm = blockIdx.y*64, bn = blockIdx.x*64;
  f32x4 acc[2][2] = {};
  for(int k0=0; k0<K; k0+=64){
    #pragma unroll
    for(int rep=0; rep<2; rep++){
      int q = tid + rep*256;
      int row = q>>3;
      int scb = ((q&7)*16) ^ ((row&7)<<4);
      const __bf16* srcA = A  + (size_t)(bm+row)*K + k0 + (scb>>1);
      const __bf16* srcB = Bt + (size_t)(bn+row)*K + k0 + (scb>>1);
      __builtin_amdgcn_global_load_lds(
        (const __attribute__((address_space(1))) void*)srcA,
        (__attribute__((address_space(3))) void*)((char*)As + q*16), 16, 0, 0);
      __builtin_amdgcn_global_load_lds(
        (const __attribute__((address_space(1))) void*)srcB,
        (__attribute__((address_space(3))) void*)((char*)Bs + q*16), 16, 0, 0);
    }
    __syncthreads();
    #pragma unroll
    for(int ks=0; ks<2; ks++){
      bf16x8 a[2], b[2];
      #pragma unroll
      for(int i=0;i<2;i++){
        int row = wr*32 + i*16 + l15;
        int byte_ = row*128 + ks*64 + g*16; byte_ ^= (row&7)<<4;
        a[i] = *(const bf16x8*)((const char*)As + byte_);
      }
      #pragma unroll
      for(int j=0;j<2;j++){
        int row = wc*32 + j*16 + l15;
        int byte_ = row*128 + ks*64 + g*16; byte_ ^= (row&7)<<4;
        b[j] = *(const bf16x8*)((const char*)Bs + byte_);
      }
      #pragma unroll
      for(int i=0;i<2;i++)
        #pragma unroll
        for(int j=0;j<2;j++)
          acc[i][j] = __builtin_amdgcn_mfma_f32_16x16x32_bf16(a[i], b[j], acc[i][j], 0, 0, 0);
    }
    __syncthreads();
  }
  #pragma unroll
  for(int i=0;i<2;i++){
    #pragma unroll
    for(int j=0;j<2;j++){
      int col = bn + wc*32 + j*16 + l15;
      float bv = bias[col];
      #pragma unroll
      for(int r=0;r<4;r++){
        int rowg = bm + wr*32 + i*16 + g*4 + r;
        float v = acc[i][j][r] + bv;
        if(MODE==1) v += add[(size_t)rowg*N + col];
        if(MODE==2){
          v = 0.5f*v*(1.0f + erff(v*0.70710678118654752f));
          outb[(size_t)rowg*N + col] = (__bf16)v;
        } else if(MODE==3){
          outb[(size_t)rowg*N + col] = (__bf16)v;
        } else {
          outf[(size_t)rowg*N + col] = v;
        }
      }
    }
  }
}

// Fused Wo-GEMM + residual + LN2: block owns 16 FULL rows (N=256), 4 waves =
// 4 col-chunks. Writes hbuf (fp32, FF2 residual) and hn (bf16, LN2 output).
__global__ __launch_bounds__(256) void k_wln(const __bf16* __restrict__ A, const __bf16* __restrict__ Bt,
                    const float* __restrict__ bias, const float* __restrict__ add,
                    const float* __restrict__ g2, const float* __restrict__ be2,
                    float* __restrict__ hbuf, __bf16* __restrict__ hn){
  __shared__ __bf16 As[16*64];    // 2KB
  __shared__ __bf16 Bs[256*64];   // 32KB
  __shared__ float partS[64], partQ[64], muv[16], invv[16];
  const int tid = threadIdx.x;
  const int lane = tid & 63;
  const int w = tid >> 6;
  const int l15 = lane & 15, g = lane >> 4;
  const int bm = blockIdx.x*16;
  const int K = 256, N = 256;
  f32x4 acc[4] = {};
  for(int k0=0; k0<K; k0+=64){
    if(tid < 128){
      int q = tid;
      int row = q>>3;
      int scb = ((q&7)*16) ^ ((row&7)<<4);
      const __bf16* srcA = A + (size_t)(bm+row)*K + k0 + (scb>>1);
      __builtin_amdgcn_global_load_lds(
        (const __attribute__((address_space(1))) void*)srcA,
        (__attribute__((address_space(3))) void*)((char*)As + q*16), 16, 0, 0);
    }
    #pragma unroll
    for(int rep=0; rep<8; rep++){
      int q = tid + rep*256;
      int row = q>>3;
      int scb = ((q&7)*16) ^ ((row&7)<<4);
      const __bf16* srcB = Bt + (size_t)row*K + k0 + (scb>>1);
      __builtin_amdgcn_global_load_lds(
        (const __attribute__((address_space(1))) void*)srcB,
        (__attribute__((address_space(3))) void*)((char*)Bs + q*16), 16, 0, 0);
    }
    __syncthreads();
    #pragma unroll
    for(int ks=0; ks<2; ks++){
      bf16x8 a, b[4];
      { int row = l15;
        int byte_ = row*128 + ks*64 + g*16; byte_ ^= (row&7)<<4;
        a = *(const bf16x8*)((const char*)As + byte_); }
      #pragma unroll
      for(int j=0;j<4;j++){
        int row = w*64 + j*16 + l15;
        int byte_ = row*128 + ks*64 + g*16; byte_ ^= (row&7)<<4;
        b[j] = *(const bf16x8*)((const char*)Bs + byte_);
      }
      #pragma unroll
      for(int j=0;j<4;j++)
        acc[j] = __builtin_amdgcn_mfma_f32_16x16x32_bf16(a, b[j], acc[j], 0, 0, 0);
    }
    __syncthreads();
  }
  float v[4][4];
  #pragma unroll
  for(int j=0;j<4;j++){
    int col = w*64 + j*16 + l15;
    float bv = bias[col];
    #pragma unroll
    for(int r=0;r<4;r++){
      int rowg = bm + g*4 + r;
      v[j][r] = acc[j][r] + bv + add[(size_t)rowg*N + col];
    }
  }
  float s[4], qq[4];
  #pragma unroll
  for(int r=0;r<4;r++){
    s[r] = v[0][r]+v[1][r]+v[2][r]+v[3][r];
    qq[r] = v[0][r]*v[0][r]+v[1][r]*v[1][r]+v[2][r]*v[2][r]+v[3][r]*v[3][r];
  }
  #pragma unroll
  for(int m=8;m>=1;m>>=1){
    #pragma unroll
    for(int r=0;r<4;r++){ s[r] += __shfl_xor(s[r],m); qq[r] += __shfl_xor(qq[r],m); }
  }
  if(l15==0){
    #pragma unroll
    for(int r=0;r<4;r++){ partS[w*16 + g*4 + r] = s[r]; partQ[w*16 + g*4 + r] = qq[r]; }
  }
  __syncthreads();
  if(tid < 16){
    float S = partS[tid] + partS[16+tid] + partS[32+tid] + partS[48+tid];
    float Q = partQ[tid] + partQ[16+tid] + partQ[32+tid] + partQ[48+tid];
    float mu = S * (1.0f/256.0f);
    float var = Q * (1.0f/256.0f) - mu*mu;
    muv[tid] = mu;
    invv[tid] = rsqrtf(var + 1e-5f);
  }
  __syncthreads();
  #pragma unroll
  for(int j=0;j<4;j++){
    int col = w*64 + j*16 + l15;
    float gv = g2[col], bev = be2[col];
    #pragma unroll
    for(int r=0;r<4;r++){
      int rowg = bm + g*4 + r;
      float mu = muv[g*4+r], iv = invv[g*4+r];
      hbuf[(size_t)rowg*N + col] = v[j][r];
      hn[(size_t)rowg*N + col] = (__bf16)(gv*(v[j][r]-mu)*iv + bev);
    }
  }
}

// merged dispatch: blocks [0,2048) = prop F1->F2 (2 rows each, 256 thr);
// blocks [2048,2816) = QKV GEMM tiles (bf16 out, N=768, K=256).
__global__ __launch_bounds__(256) void k_pq(const int* __restrict__ cursor, const int* __restrict__ nsrc,
                    const unsigned* __restrict__ F1, unsigned* __restrict__ F2,
                    const __bf16* __restrict__ A, const __bf16* __restrict__ Bt,
                    const float* __restrict__ bias, __bf16* __restrict__ outb){
  __shared__ __bf16 As[64*64];
  __shared__ __bf16 Bs[64*64];
  const int b = blockIdx.x;
  const int tid = threadIdx.x;
  if(b < 2048){
    int d = b*2 + (tid>>7);
    int w_ = tid & 127;
    int cdeg = cursor[d]; if(cdeg > MAXD) cdeg = MAXD;
    const int* row = nsrc + d*MAXD;
    unsigned v = 0;
    for(int i=0;i<cdeg;i++) v |= F1[(size_t)row[i]*FW + w_];
    F2[(size_t)d*FW + w_] = v;
    return;
  }
  const int bx = b - 2048;
  const int N = 768, K = 256;
  const int bm = (bx/12)*64, bn = (bx%12)*64;
  const int lane = tid & 63;
  const int w = tid >> 6;
  const int wr = w >> 1, wc = w & 1;
  const int l15 = lane & 15, g = lane >> 4;
  f32x4 acc[2][2] = {};
  for(int k0=0; k0<K; k0+=64){
    #pragma unroll
    for(int rep=0; rep<2; rep++){
      int q = tid + rep*256;
      int row = q>>3;
      int scb = ((q&7)*16) ^ ((row&7)<<4);
      const __bf16* srcA = A  + (size_t)(bm+row)*K + k0 + (scb>>1);
      const __bf16* srcB = Bt + (size_t)(bn+row)*K + k0 + (scb>>1);
      __builtin_amdgcn_global_load_lds(
        (const __attribute__((address_space(1))) void*)srcA,
        (__attribute__((address_space(3))) void*)((char*)As + q*16), 16, 0, 0);
      __builtin_amdgcn_global_load_lds(
        (const __attribute__((address_space(1))) void*)srcB,
        (__attribute__((address_space(3))) void*)((char*)Bs + q*16), 16, 0, 0);
    }
    __syncthreads();
    #pragma unroll
    for(int ks=0; ks<2; ks++){
      bf16x8 a[2], bb[2];
      #pragma unroll
      for(int i=0;i<2;i++){
        int row = wr*32 + i*16 + l15;
        int byte_ = row*128 + ks*64 + g*16; byte_ ^= (row&7)<<4;
        a[i] = *(const bf16x8*)((const char*)As + byte_);
      }
      #pragma unroll
      for(int j=0;j<2;j++){
        int row = wc*32 + j*16 + l15;
        int byte_ = row*128 + ks*64 + g*16; byte_ ^= (row&7)<<4;
        bb[j] = *(const bf16x8*)((const char*)Bs + byte_);
      }
      #pragma unroll
      for(int i=0;i<2;i++)
        #pragma unroll
        for(int j=0;j<2;j++)
          acc[i][j] = __builtin_amdgcn_mfma_f32_16x16x32_bf16(a[i], bb[j], acc[i][j], 0, 0, 0);
    }
    __syncthreads();
  }
  #pragma unroll
  for(int i=0;i<2;i++){
    #pragma unroll
    for(int j=0;j<2;j++){
      int col = bn + wc*32 + j*16 + l15;
      float bv = bias[col];
      #pragma unroll
      for(int r=0;r<4;r++){
        int rowg = bm + wr*32 + i*16 + g*4 + r;
        outb[(size_t)rowg*N + col] = (__bf16)(acc[i][j][r] + bv);
      }
    }
  }
}

// Fused scores + segment softmax + V-aggregation. Parallel lazy spd3 probe.
// Phase 3 vectorized: 8 edge-slots x 32 lanes, bf16x8 V loads (16B/lane),
// shfl_xor(32) slot-pair reduce + LDS cross-wave reduce, bf16x8 msg store.
__global__ void k_sagg(const int* __restrict__ nsrc, const int* __restrict__ cursor,
                       const __bf16* __restrict__ QKV,
                       const unsigned* __restrict__ F1, const unsigned* __restrict__ F2,
                       const float* __restrict__ spde, __bf16* __restrict__ msg){
  __shared__ float scs[MAXD][9];
  __shared__ int   sl[MAXD];
  __shared__ int   spi[MAXD];
  __shared__ float red[4][32][8];   // 4KB cross-wave reduce
  const int d = blockIdx.x;
  const int t = threadIdx.x;
  const int wo = d>>5; const unsigned bb = 1u << (d&31);
  int deg = cursor[d]; if(deg > MAXD) deg = MAXD;
  if(t < deg){
    int s = nsrc[d*MAXD+t];
    sl[t] = s;
    int sp = 4;
    if(F1[(size_t)s*FW + wo] & bb) sp = 1;
    else if(F2[(size_t)s*FW + wo] & bb) sp = 2;
    spi[t] = sp;
  }
  __syncthreads();
  // parallel spd3 probe: edge i = t>>3 (stride 32), probe-lane j = t&7
  { const int j = t & 7;
    for(int i = t>>3; i < deg; i += 32){
      if(spi[i] == 4){
        int s = sl[i];
        int sdeg = cursor[s]; if(sdeg > MAXD) sdeg = MAXD;
        const int* srow = nsrc + s*MAXD;
        for(int k=j; k<sdeg; k+=8){
          if(F2[(size_t)srow[k]*FW + wo] & bb){ spi[i] = 3; break; }
        }
      }
    }
  }
  __syncthreads();
  // phase 1: (edge, head, quarter)-parallel scores
  { const int i0 = t>>5, h = (t>>2)&7, q = t&3;
    bf16x8 qv = *(const bf16x8*)(QKV + (size_t)d*768 + h*DHD + q*8);
    for(int i=i0; i<deg; i+=8){
      bf16x8 kv = *(const bf16x8*)(QKV + (size_t)sl[i]*768 + 256 + h*DHD + q*8);
      float p = 0.f;
      #pragma unroll
      for(int u=0;u<8;u++) p += (float)qv[u] * (float)kv[u];
      p += __shfl_xor(p,1);
      p += __shfl_xor(p,2);
      if(q==0) scs[i][h] = p * 0.17677669529663687f + spde[spi[i]*HH + h];
    }
  }
  __syncthreads();
  // phase 2: segment softmax per head
  { const int h = t >> 5, l = t & 31;
    float m = -3.0e38f;
    for(int i=l;i<deg;i+=32) m = fmaxf(m, scs[i][h]);
    #pragma unroll
    for(int mk=16;mk>=1;mk>>=1) m = fmaxf(m, __shfl_xor(m,mk));
    float ss = 0.f;
    for(int i=l;i<deg;i+=32) ss += expf(scs[i][h]-m);
    #pragma unroll
    for(int mk=16;mk>=1;mk>>=1) ss += __shfl_xor(ss,mk);
    float inv = (ss>0.f) ? 1.f/ss : 1.f;
    for(int i=l;i<deg;i+=32) scs[i][h] = expf(scs[i][h]-m)*inv;
  }
  __syncthreads();
  // phase 3 (vectorized): slot i0 = t>>5, lane l = t&31 covers channels l*8..+8
  { const int i0 = t>>5, l = t&31, h = l>>2, wv_ = t>>6;
    float p[8] = {0.f,0.f,0.f,0.f,0.f,0.f,0.f,0.f};
    for(int i=i0; i<deg; i+=8){
      float wgt = scs[i][h];
      bf16x8 v8 = *(const bf16x8*)(QKV + (size_t)sl[i]*768 + 512 + l*8);
      #pragma unroll
      for(int u=0;u<8;u++) p[u] += wgt * (float)v8[u];
    }
    #pragma unroll
    for(int u=0;u<8;u++) p[u] += __shfl_xor(p[u], 32);
    if((t & 32) == 0){
      #pragma unroll
      for(int u=0;u<8;u++) red[wv_][l][u] = p[u];
    }
    __syncthreads();
    if(t < 32){
      bf16x8 o;
      #pragma unroll
      for(int u=0;u<8;u++)
        o[u] = (__bf16)(red[0][t][u] + red[1][t][u] + red[2][t][u] + red[3][t][u]);
      *(bf16x8*)(msg + (size_t)d*CC + t*8) = o;
    }
  }
}

extern "C" void kernel_launch(void* const* d_in, const int* in_sizes, int n_in,
                              void* d_out, int out_size, void* d_ws, size_t ws_size,
                              hipStream_t stream){
  const float* x  = (const float*)d_in[0];
  const int*  ei  = (const int*)d_in[1];
  const float* Wq = (const float*)d_in[2];  const float* bq = (const float*)d_in[3];
  const float* Wk = (const float*)d_in[4];  const float* bk = (const float*)d_in[5];
  const float* Wv = (const float*)d_in[6];  const float* bv = (const float*)d_in[7];
  const float* Wo = (const float*)d_in[8];  const float* bo = (const float*)d_in[9];
  const float* W1 = (const float*)d_in[10]; const float* b1 = (const float*)d_in[11];
  const float* W2 = (const float*)d_in[12]; const float* b2 = (const float*)d_in[13];
  const float* g1 = (const float*)d_in[14]; const float* be1= (const float*)d_in[15];
  const float* g2 = (const float*)d_in[16]; const float* be2= (const float*)d_in[17];
  const float* spde = (const float*)d_in[18];
  const float* iemb = (const float*)d_in[19];
  const float* oemb = (const float*)d_in[20];
  const float* etb  = (const float*)d_in[21]; (void)etb; // cancels in softmax
  const int* src = ei;
  const int* dst = ei + EE;
  float* out = (float*)d_out;

  const size_t NC = (size_t)NN*CC;       // 1,048,576 floats
  float* ws   = (float*)d_ws;
  // ---- layout in float words ----
  float* x_in = ws;                                   // [0, NC)
  float* hbuf = ws + NC;                              // [NC, 2NC)
  int* cursor = (int*)(ws + 2*NC);                    // NN ints (= indeg)
  int* outdeg = cursor + NN;                          // NN ints
  unsigned* F1 = (unsigned*)(ws + 2*NC + 12288);
  unsigned* F2 = F1 + (size_t)NN*FW;                  // (F3 region unused)
  __bf16* QKV  = (__bf16*)(ws + 3682304);             // [3,682,304 , 5,255,168)
  int* nsrc    = (int*)(ws + 5255168);                // NN*MAXD = 262,144 ints
  __bf16* xn_bf  = (__bf16*)(ws + 5517312);           // 262,144 words
  __bf16* msg_bf = (__bf16*)(ws + 6041600);           // 262,144 words
  __bf16* WqkvT  = (__bf16*)(ws + 6565888);           // 98,304 words
  __bf16* WoT    = WqkvT + 196608;
  __bf16* W1T    = WoT + 65536;
  __bf16* W2T    = W1T + 262144;                      // ends 6,959,104
  float* bqkv    = ws + 6959104;                      // 768
  // late-phase reuse (dead regions after sagg):
  __bf16* ff1_bf = (__bf16*)(ws + 2*NC);              // [2NC,4NC) over cursor/outdeg/F1-F2
  __bf16* hn_bf  = (__bf16*)(ws + 4*NC);              // [4NC,4.5NC) over QKV head

  // 1: weight prep + zero cursor|outdeg
  k_pre<<<225,256,0,stream>>>(Wq,Wk,Wv,Wo,W1,W2,bq,bk,bv,WqkvT,WoT,W1T,W2T,bqkv,cursor);
  // 2: single-pass degree count + fixed-slot CSR scatter
  k_scatter<<<EE/256,256,0,stream>>>(src,dst,cursor,outdeg,nsrc);
  // 3: F1 build + x_in/LN1
  k_mid<<<3072,256,0,stream>>>(cursor,nsrc,F1,x,outdeg,iemb,oemb,g1,be1,x_in,xn_bf);
  // 4: merged prop F1->F2 + QKV GEMM
  k_pq<<<2816,256,0,stream>>>(cursor,nsrc,F1,F2,xn_bf,WqkvT,bqkv,QKV);
  // 5: fused attention (parallel lazy spd3 probe, vectorized V-agg)
  k_sagg<<<NN,256,0,stream>>>(nsrc,cursor,QKV,F1,F2,spde,msg_bf);
  // 6: fused Wo-GEMM + residual + LN2
  k_wln<<<NN/16,256,0,stream>>>(msg_bf, WoT, bo, x_in, g2, be2, hbuf, hn_bf);
  // 7-8: FFN
  dim3 gf1(1024/64, NN/64);
  k_bgemm<2><<<gf1,256,0,stream>>>(hn_bf, W1T, b1, nullptr, nullptr, ff1_bf, NN, 1024, 256);
  dim3 gf2(256/64, NN/64);
  k_bgemm<1><<<gf2,256,0,stream>>>(ff1_bf, W2T, b2, hbuf, out, nullptr, NN, 256, 1024);
}